// Round 1
// 223.674 us; speedup vs baseline: 1.0710x; 1.0710x over previous
//
#include <hip/hip_runtime.h>
#include <math.h>

#define N_TOK 16384
#define D_MODEL 2048
#define N_EXP 64
#define CAPACITY 640
#define NREP 8

#define BK 32
#define NSTAGE (D_MODEL / BK)  // 64
#define LP 48                  // padded LDS row length in halves (96B, 16B-aligned)

typedef __attribute__((ext_vector_type(8))) _Float16 h8;
typedef __attribute__((ext_vector_type(4))) float f4;

// ---------------- K12: fused MFMA fp16-split GEMM + softmax/top2/hist/z -----
// 256 blocks x 256 thr; block = 64 tokens x 64 experts x K=2048.
// 3-term split: logits = (xh·wh' + (xl'·wh' + xh·wl')·2^-10)·2^-10, W'=W·2^10.
__global__ __launch_bounds__(256, 1) void k12_gemm_softmax(
    const float* __restrict__ x, const float* __restrict__ W,
    float* __restrict__ rw_out, int2* __restrict__ top12,
    float2* __restrict__ wts, int* __restrict__ histR,
    float* __restrict__ zR) {
  __shared__ _Float16 XH[2][64][LP];
  __shared__ _Float16 XL[2][64][LP];
  __shared__ _Float16 WHs[2][64][LP];
  __shared__ _Float16 WLs[2][64][LP];
  __shared__ float slog[64][65];  // logits tile for softmax tail
  __shared__ float zred[4];

  const int t = threadIdx.x;
  const int lane = t & 63;
  const int wid = t >> 6;
  const int m0 = blockIdx.x * 64;
  const int rep = blockIdx.x & (NREP - 1);

  const int srow = t >> 2;       // staging row: token (x) / expert (W)
  const int scol = (t & 3) * 8;  // k-col base (floats), 32B-aligned
  const float* xg = x + (size_t)(m0 + srow) * D_MODEL + scol;
  const float* wg = W + (size_t)srow * D_MODEL + scol;

  // depth-2 register prefetch: RA = stage s, RB = stage s+1
  float4 xa0 = *(const float4*)(xg);
  float4 xa1 = *(const float4*)(xg + 4);
  float4 wa0 = *(const float4*)(wg);
  float4 wa1 = *(const float4*)(wg + 4);
  float4 xb0 = *(const float4*)(xg + BK);
  float4 xb1 = *(const float4*)(xg + BK + 4);
  float4 wb0 = *(const float4*)(wg + BK);
  float4 wb1 = *(const float4*)(wg + BK + 4);

  f4 acc1[4], acc2[4];
#pragma unroll
  for (int i = 0; i < 4; i++) {
    acc1[i] = (f4)(0.f);
    acc2[i] = (f4)(0.f);
  }

#define CVT_STORE(buf, X0, X1, W0, W1)                              \
  {                                                                 \
    float xv[8] = {X0.x, X0.y, X0.z, X0.w, X1.x, X1.y, X1.z, X1.w}; \
    float wv[8] = {W0.x, W0.y, W0.z, W0.w, W1.x, W1.y, W1.z, W1.w}; \
    h8 cxh, cxl, cwh, cwl;                                          \
    _Pragma("unroll") for (int j = 0; j < 8; j++) {                 \
      _Float16 h = (_Float16)xv[j];                                 \
      cxh[j] = h;                                                   \
      cxl[j] = (_Float16)((xv[j] - (float)h) * 1024.f);             \
      float wsc = wv[j] * 1024.f;                                   \
      _Float16 hw = (_Float16)wsc;                                  \
      cwh[j] = hw;                                                  \
      cwl[j] = (_Float16)((wsc - (float)hw) * 1024.f);              \
    }                                                               \
    *(h8*)&XH[buf][srow][scol] = cxh;                               \
    *(h8*)&XL[buf][srow][scol] = cxl;                               \
    *(h8*)&WHs[buf][srow][scol] = cwh;                              \
    *(h8*)&WLs[buf][srow][scol] = cwl;                              \
  }

#define COMPUTE(buf)                                                          \
  {                                                                           \
    const int frow = lane & 15;                                               \
    const int fk = (lane >> 4) * 8;                                           \
    h8 ah = *(const h8*)&XH[buf][wid * 16 + frow][fk];                        \
    h8 al = *(const h8*)&XL[buf][wid * 16 + frow][fk];                        \
    _Pragma("unroll") for (int nt = 0; nt < 4; nt++) {                        \
      h8 bh = *(const h8*)&WHs[buf][nt * 16 + frow][fk];                      \
      h8 bl = *(const h8*)&WLs[buf][nt * 16 + frow][fk];                      \
      acc1[nt] =                                                              \
          __builtin_amdgcn_mfma_f32_16x16x32_f16(ah, bh, acc1[nt], 0, 0, 0);  \
      acc2[nt] =                                                              \
          __builtin_amdgcn_mfma_f32_16x16x32_f16(al, bh, acc2[nt], 0, 0, 0);  \
      acc2[nt] =                                                              \
          __builtin_amdgcn_mfma_f32_16x16x32_f16(ah, bl, acc2[nt], 0, 0, 0);  \
    }                                                                         \
  }

  CVT_STORE(0, xa0, xa1, wa0, wa1);
  for (int it = 0; it < NSTAGE / 2; it++) {
    __syncthreads();  // buf0 of this pair visible; prev pair's reads done
    const int s2 = 2 * it + 2;
    if (s2 < NSTAGE) {
      xa0 = *(const float4*)(xg + s2 * BK);
      xa1 = *(const float4*)(xg + s2 * BK + 4);
      wa0 = *(const float4*)(wg + s2 * BK);
      wa1 = *(const float4*)(wg + s2 * BK + 4);
    }
    COMPUTE(0);
    CVT_STORE(1, xb0, xb1, wb0, wb1);
    __syncthreads();
    const int s3 = 2 * it + 3;
    if (s3 < NSTAGE) {
      xb0 = *(const float4*)(xg + s3 * BK);
      xb1 = *(const float4*)(xg + s3 * BK + 4);
      wb0 = *(const float4*)(wg + s3 * BK);
      wb1 = *(const float4*)(wg + s3 * BK + 4);
    }
    COMPUTE(1);
    if (it + 1 < NSTAGE / 2) CVT_STORE(0, xa0, xa1, wa0, wa1);
  }

  // epilogue: C layout col=lane&15 (expert), row=(lane>>4)*4+r (token)
  const int cg = lane >> 4, ci = lane & 15;
#pragma unroll
  for (int nt = 0; nt < 4; nt++)
#pragma unroll
    for (int r = 0; r < 4; r++) {
      const float v =
          (acc1[nt][r] + acc2[nt][r] * 0.0009765625f) * 0.0009765625f;
      slog[wid * 16 + cg * 4 + r][nt * 16 + ci] = v;  // wave-local rows
    }

  // ---- softmax / top2 / hist / z tail (k2 logic, per-token, wave-local) ----
  float z_acc = 0.f;
  for (int tt = 0; tt < 16; tt++) {
    const int tloc = wid * 16 + tt;
    const int n = m0 + tloc;
    const float v = slog[tloc][lane];
    z_acc += v * v;
    float mx = v;
#pragma unroll
    for (int off = 32; off; off >>= 1) mx = fmaxf(mx, __shfl_xor(mx, off));
    const float p = __expf(v - mx);
    float ssum = p;
#pragma unroll
    for (int off = 32; off; off >>= 1) ssum += __shfl_xor(ssum, off);
    const float rw = p / ssum;
    rw_out[(size_t)n * N_EXP + lane] = rw;

    const unsigned long long b1 = __ballot(v == mx);
    const int i1 = __builtin_ctzll(b1);
    float v2 = (lane == i1) ? -INFINITY : v;
#pragma unroll
    for (int off = 32; off; off >>= 1) v2 = fmaxf(v2, __shfl_xor(v2, off));
    const unsigned long long b2 = __ballot(v == v2) & ~(1ull << i1);
    const int i2 = __builtin_ctzll(b2);
    const float rw1 = __shfl(rw, i1);
    const float rw2 = __shfl(rw, i2);
    if (lane == 0) {
      const float denom = rw1 + rw2 + 1e-8f;
      top12[n] = make_int2(i1, i2);
      wts[n] = make_float2(rw1 / denom, rw2 / denom);
      atomicAdd(&histR[(rep * N_EXP + i1) * 16], 1);
    }
  }
#pragma unroll
  for (int off = 32; off; off >>= 1) z_acc += __shfl_xor(z_acc, off);
  if (lane == 0) zred[wid] = z_acc;
  __syncthreads();
  if (t == 0) atomicAdd(&zR[rep * 16], zred[0] + zred[1] + zred[2] + zred[3]);
}

// ---------------- K3: wave-per-token dispatch mask + counts -----------------
__global__ __launch_bounds__(256) void k3_dispatch(
    const int2* __restrict__ top12, const float2* __restrict__ wts,
    const int* __restrict__ histR, float* __restrict__ mask_out,
    float* __restrict__ cntR) {
  const int lane = threadIdx.x & 63;
  const int wid = threadIdx.x >> 6;
  const int n = blockIdx.x * 4 + wid;
  const int rep = blockIdx.x & (NREP - 1);

  const int2 ij = top12[n];
  const float2 w = wts[n];
  int h = 0;
#pragma unroll
  for (int r = 0; r < NREP; r++) h += histR[(r * N_EXP + ij.y) * 16];
  const bool allowed = h < CAPACITY;
  const float ssum = w.x + (allowed ? w.y : 0.f);
  const float inv = 1.f / (ssum + 1e-8f);
  float val = 0.f;
  if (lane == ij.x) val = w.x * inv;
  else if (allowed && lane == ij.y) val = w.y * inv;
  mask_out[(size_t)n * N_EXP + lane] = val;
  if (val != 0.f) atomicAdd(&cntR[(rep * N_EXP + lane) * 16], val);
}

// ---------------- K4: scalar loss -------------------------------------------
__global__ void k4_loss(const float* __restrict__ cntR,
                        const float* __restrict__ zR,
                        float* __restrict__ loss_out) {
  const int lane = threadIdx.x;
  float c = 0.f;
#pragma unroll
  for (int r = 0; r < NREP; r++) c += cntR[(r * N_EXP + lane) * 16];
  const float d = (c - 512.0f) * (1.0f / 16384.0f);
  float v = d * d;
#pragma unroll
  for (int off = 32; off; off >>= 1) v += __shfl_xor(v, off);
  if (lane == 0) {
    float z = 0.f;
#pragma unroll
    for (int r = 0; r < NREP; r++) z += zR[r * 16];
    const float lb = v * (1.0f / 64.0f);
    loss_out[0] = 0.001f * (z * (1.0f / (16384.0f * 64.0f))) + 0.001f * lb;
  }
}

extern "C" void kernel_launch(void* const* d_in, const int* in_sizes, int n_in,
                              void* d_out, int out_size, void* d_ws,
                              size_t ws_size, hipStream_t stream) {
  const float* x = (const float*)d_in[0];
  const float* W = (const float*)d_in[1];
  float* out = (float*)d_out;
  float* rw_out = out;
  float* mask_out = out + (size_t)N_TOK * N_EXP;
  float* loss_out = out + 2 * (size_t)N_TOK * N_EXP;

  char* ws = (char*)d_ws;
  int* histR = (int*)ws;                    // 32 KB (8 reps x 64 x stride16)
  float* cntR = (float*)(ws + 32768);       // 32 KB
  float* zR = (float*)(ws + 65536);         // 512 B
  int2* top12 = (int2*)(ws + 131072);       // 128 KB
  float2* wts = (float2*)(ws + 262144);     // 128 KB

  hipMemsetAsync(histR, 0, 65536 + 512, stream);
  k12_gemm_softmax<<<256, 256, 0, stream>>>(x, W, rw_out, top12, wts, histR,
                                            zR);
  k3_dispatch<<<N_TOK / 4, 256, 0, stream>>>(top12, wts, histR, mask_out,
                                             cntR);
  k4_loss<<<1, 64, 0, stream>>>(cntR, zR, loss_out);
}